// Round 6
// baseline (80.355 us; speedup 1.0000x reference)
//
#include <hip/hip_runtime.h>

// Helmholtz loss, fully reduced:
//   patch(b,h,w) = w^T H w, w from per-pixel linear fields,
//   H = M^T (a1*C1 + a2*C2 + a3*C3sym) M  (host, double precision).
// Round-6 structure: block = 4 waves = 4 patch rows x 512 cols.
// Staging via __builtin_amdgcn_global_load_lds (no VGPR destinations ->
// nothing for the scheduler to sink; rounds 2-5 showed VGPR-dest loads
// always get re-batched into serialized issue->wait->consume groups).
// 5 rows x 4ch = 40 x 1KB async units -> one vmcnt drain at the barrier ->
// pure-LDS compute (contiguous float4 reads, conflict-free).
// Fused last-block final reduction (proven rounds 3-5).

struct HParams {
    float u0, u1, u2, u3;
    float H00, H11, H22, H33;
    float H01_2, H02_2, H03_2, H12_2, H13_2, H23_2;
};

#define BSIZE 256
#define NBLK  2048

typedef __attribute__((address_space(1))) const void gvoid_t;
typedef __attribute__((address_space(3))) void ldsvoid_t;

__device__ __forceinline__ void gload_lds16(const float* g, float* l) {
    __builtin_amdgcn_global_load_lds((gvoid_t*)g, (ldsvoid_t*)l, 16, 0, 0);
}

__device__ __forceinline__ float f4get(const float4& v, int k) {
    switch (k & 3) { case 0: return v.x; case 1: return v.y; case 2: return v.z; default: return v.w; }
}

__global__ __launch_bounds__(BSIZE, 4) void helm_main(const float* __restrict__ x,
                                                      double* __restrict__ partial,
                                                      unsigned int* __restrict__ counter,
                                                      float* __restrict__ out,
                                                      HParams P)
{
    __shared__ float lds[5 * 4 * 512];     // 40960 B: [row 0..4][ch 0..3][col 0..511]

    const int t    = threadIdx.x;
    const int lane = t & 63;
    const int w    = t >> 6;               // wave id == local patch row (0..3)
    const int blk  = blockIdx.x;
    const int b    = blk >> 7;             // image 0..15
    const int win  = blk & 127;            // window 0..127
    const int h0   = win * 4;

    const float* xb = x + (size_t)b * (4u * 512u * 512u);

    // ---- async stage: 40 x 1KB units, 10 per wave, zero VGPR destinations ----
    #pragma unroll
    for (int i = 0; i < 10; ++i) {
        const int u   = w * 10 + i;        // 0..39
        const int row = u >> 3;            // 0..4
        const int ch  = (u >> 1) & 3;      // 0..3
        const int g   = u & 1;             // column group (0: 0..255, 1: 256..511)
        const int rg  = min(h0 + row, 511);
        const float* src = xb + ((size_t)ch * 512u + (size_t)rg) * 512u + g * 256 + lane * 4;
        float* dst = &lds[(row * 4 + ch) * 512 + g * 256];   // +lane*16B applied by HW
        gload_lds16(src, dst);
    }
    __syncthreads();   // one vmcnt drain for all 40 units

    // ---- compute: wave w handles patch row pr = h0 + w ----
    const int pr = h0 + w;
    double acc = 0.0;
    if (pr < 511) {
        const float* ldst = &lds[(w * 4) * 512];        // top data row
        const float* ldsb = &lds[((w + 1) * 4) * 512];  // bottom data row
        float4 Xt[4][2], Xb[4][2];
        #pragma unroll
        for (int ch = 0; ch < 4; ++ch) {
            #pragma unroll
            for (int g = 0; g < 2; ++g) {
                Xt[ch][g] = *(const float4*)(ldst + ch * 512 + g * 256 + lane * 4);
                Xb[ch][g] = *(const float4*)(ldsb + ch * 512 + g * 256 + lane * 4);
            }
        }
        // per-col fields -> patch w-vector components
        float aV[2][4], bV[2][4], cV[2][4];
        #pragma unroll
        for (int g = 0; g < 2; ++g) {
            #pragma unroll
            for (int j = 0; j < 4; ++j) {
                const float xt0 = f4get(Xt[0][g], j), xt1 = f4get(Xt[1][g], j);
                const float xt2 = f4get(Xt[2][g], j), xt3 = f4get(Xt[3][g], j);
                const float xb0 = f4get(Xb[0][g], j), xb1 = f4get(Xb[1][g], j);
                const float xb2 = f4get(Xb[2][g], j), xb3 = f4get(Xb[3][g], j);
                const float t0 = P.u0 * xt0;
                const float T1 = fmaf(P.u2, xt3, t0);
                const float T2 = fmaf(P.u2, xt1, t0);
                const float T4 = fmaf(P.u2, xt3, P.u0 * xt2);
                const float f3 = fmaf(P.u3, xb1, P.u1 * xb0);
                const float f5 = fmaf(P.u3, xb3, P.u1 * xb2);
                aV[g][j] = T1 + f3;
                bV[g][j] = T2 + f3;
                cV[g][j] = T4 + f5;
            }
        }
        // horizontal neighbors: in-lane for j<3; lane+1 for j==3; col255->256 seam
        const float bn0 = __shfl_down(bV[0][0], 1, 64);
        const float cn0 = __shfl_down(cV[0][0], 1, 64);
        const float bn1 = __shfl_down(bV[1][0], 1, 64);
        const float cn1 = __shfl_down(cV[1][0], 1, 64);
        const float bx  = __shfl(bV[1][0], 0, 64);   // field at col 256
        const float cx  = __shfl(cV[1][0], 0, 64);

        float rowsum = 0.0f;
        #pragma unroll
        for (int g = 0; g < 2; ++g) {
            const float bnn = (g == 0) ? ((lane < 63) ? bn0 : bx) : bn1;
            const float cnn = (g == 0) ? ((lane < 63) ? cn0 : cx) : cn1;
            #pragma unroll
            for (int j = 0; j < 4; ++j) {
                const float w0 = aV[g][j];
                const float w1 = (j < 3) ? bV[g][j + 1] : bnn;
                const float w2 = cV[g][j];
                const float w3 = (j < 3) ? cV[g][j + 1] : cnn;
                const float q0 = fmaf(P.H03_2, w3, fmaf(P.H02_2, w2, fmaf(P.H01_2, w1, P.H00 * w0)));
                const float q1 = fmaf(P.H13_2, w3, fmaf(P.H12_2, w2, P.H11 * w1));
                const float q2 = fmaf(P.H23_2, w3, P.H22 * w2);
                const float q3 = P.H33 * w3;
                const float pq = fmaf(w0, q0, fmaf(w1, q1, fmaf(w2, q2, w3 * q3)));
                const bool valid = !(g == 1 && j == 3 && lane == 63);   // col 511 has no patch
                rowsum += valid ? pq : 0.0f;
            }
        }
        acc = (double)rowsum;
    }

    // ---- block reduction (LDS overlay after barrier) + fused final fold ----
    #pragma unroll
    for (int off = 32; off > 0; off >>= 1)
        acc += __shfl_down(acc, off, 64);
    __syncthreads();                        // all lds data reads complete
    double* wred = (double*)lds;            // overlay: 4 doubles + 1 int flag
    if (lane == 0) wred[w] = acc;
    __syncthreads();
    if (t == 0) {
        const double bsum = wred[0] + wred[1] + wred[2] + wred[3];
        __hip_atomic_store(&partial[blk], bsum, __ATOMIC_RELAXED, __HIP_MEMORY_SCOPE_AGENT);
        const unsigned int old = __hip_atomic_fetch_add(counter, 1u, __ATOMIC_ACQ_REL, __HIP_MEMORY_SCOPE_AGENT);
        ((int*)lds)[16] = (old == (unsigned int)(NBLK - 1)) ? 1 : 0;
    }
    __syncthreads();

    if (((int*)lds)[16]) {
        double a = 0.0;
        #pragma unroll
        for (int k = 0; k < NBLK / BSIZE; ++k)
            a += __hip_atomic_load(&partial[t + k * BSIZE], __ATOMIC_RELAXED, __HIP_MEMORY_SCOPE_AGENT);
        #pragma unroll
        for (int off = 32; off > 0; off >>= 1)
            a += __shfl_down(a, off, 64);
        __syncthreads();
        if (lane == 0) wred[w] = a;
        __syncthreads();
        if (t == 0) {
            const double sum = wred[0] + wred[1] + wred[2] + wred[3];
            out[0] = (float)(sum / (16.0 * 511.0 * 511.0));
        }
    }
}

extern "C" void kernel_launch(void* const* d_in, const int* in_sizes, int n_in,
                              void* d_out, int out_size, void* d_ws, size_t ws_size,
                              hipStream_t stream) {
    const float* x  = (const float*)d_in[0];
    float* out      = (float*)d_out;
    double* partial = (double*)d_ws;                                // NBLK doubles
    unsigned int* counter = (unsigned int*)((char*)d_ws + NBLK * sizeof(double));

    // ---- host-side constant computation (double precision) ----
    const double L = 0.01;
    double lm[7];
    lm[0] = L;
    for (int i = 1; i < 7; ++i) lm[i] = lm[i - 1] * L;

    double C1[4][4], C2[4][4] = {}, C3[4][4] = {};
    for (int i = 0; i < 4; ++i)
        for (int j = 0; j < 4; ++j)
            C1[i][j] = lm[i + j] / (double)(i + j + 1);
    C2[2][2] = 4.0 * lm[0];  C2[2][3] = 6.0 * lm[1];
    C2[3][2] = 6.0 * lm[1];  C2[3][3] = 12.0 * lm[2];
    C3[2][0] = 2.0 * lm[0];  C3[2][1] = lm[1];
    C3[2][2] = (2.0 / 3.0) * lm[2];  C3[2][3] = 0.5 * lm[3];
    C3[3][0] = 3.0 * lm[1];  C3[3][1] = 2.0 * lm[2];
    C3[3][2] = 1.5 * lm[3];  C3[3][3] = (6.0 / 5.0) * lm[4];

    const double M[4][4] = {
        {1.0, 0.0, 0.0, 0.0},
        {0.0, 0.0, 1.0, 0.0},
        {-3.0 / lm[1], 3.0 / lm[1], -2.0 / lm[0], -1.0 / lm[0]},
        { 2.0 / lm[2], -2.0 / lm[2], 1.0 / lm[1],  1.0 / lm[1]}
    };

    double s1 = 0.0, s2 = 0.0, s3 = 0.0;
    for (int i = 0; i < 4; ++i)
        for (int j = 0; j < 4; ++j) {
            s1 += C1[i][j]; s2 += C2[i][j]; s3 += C3[i][j];
        }

    const double k2 = 20.0 * 20.0;   // K*K
    const double a1 = s2 + k2 * k2 * s1 + 2.0 * k2 * s3;  // coeff of qC1
    const double a2 = s1;                                 // coeff of qC2
    const double a3 = 2.0 * s3 + 2.0 * k2 * s1;           // coeff of qC3 (+ qC3T == qC3)

    double G[4][4];
    for (int i = 0; i < 4; ++i)
        for (int j = 0; j < 4; ++j)
            G[i][j] = a1 * C1[i][j] + a2 * C2[i][j] + a3 * C3[i][j];

    double H[4][4] = {};
    for (int jj = 0; jj < 4; ++jj)
        for (int kk = 0; kk < 4; ++kk) {
            double s = 0.0;
            for (int a = 0; a < 4; ++a)
                for (int bb = 0; bb < 4; ++bb)
                    s += M[a][jj] * G[a][bb] * M[bb][kk];
            H[jj][kk] = s;
        }
    double Hs[4][4];
    for (int i = 0; i < 4; ++i)
        for (int j = 0; j < 4; ++j)
            Hs[i][j] = 0.5 * (H[i][j] + H[j][i]);

    double u[4];
    for (int j = 0; j < 4; ++j)
        u[j] = M[0][j] + M[1][j] + M[2][j] + M[3][j];

    HParams P;
    P.u0 = (float)u[0]; P.u1 = (float)u[1]; P.u2 = (float)u[2]; P.u3 = (float)u[3];
    P.H00 = (float)Hs[0][0]; P.H11 = (float)Hs[1][1];
    P.H22 = (float)Hs[2][2]; P.H33 = (float)Hs[3][3];
    P.H01_2 = (float)(2.0 * Hs[0][1]); P.H02_2 = (float)(2.0 * Hs[0][2]);
    P.H03_2 = (float)(2.0 * Hs[0][3]); P.H12_2 = (float)(2.0 * Hs[1][2]);
    P.H13_2 = (float)(2.0 * Hs[1][3]); P.H23_2 = (float)(2.0 * Hs[2][3]);

    (void)in_sizes; (void)n_in; (void)out_size; (void)ws_size;

    hipMemsetAsync(counter, 0, sizeof(unsigned int), stream);
    helm_main<<<dim3(NBLK), dim3(BSIZE), 0, stream>>>(x, partial, counter, out, P);
}